// Round 23
// baseline (743.563 us; speedup 1.0000x reference)
//
#include <hip/hip_runtime.h>
#include <hip/hip_bf16.h>
#include <cmath>

#define NNODES 50000
#define NEDGES 600000
#define NBATCH 50
#define DEGCAP 64                                 // P(Poisson(12) >= 64) ~ 4e-18: safe
#define NSLABS (NNODES/16)                        // 3125 (exact)

typedef _Float16 h16;
typedef __attribute__((ext_vector_type(2))) _Float16 h16x2;
typedef __attribute__((ext_vector_type(8))) _Float16 h16x8;
typedef __attribute__((ext_vector_type(4))) float f32x4;
typedef __attribute__((ext_vector_type(2))) float f32x2;

__device__ __forceinline__ h16x2 u2h(unsigned u){ return __builtin_bit_cast(h16x2, u); }
__device__ __forceinline__ f32x2 hpair(unsigned u){
  h16x2 h = u2h(u);
  return (f32x2){(float)h.x, (float)h.y};
}
// 16-lane-row sum via DPP (no LDS pipe): quad_perm xor1, xor2, half_mirror, mirror.
__device__ __forceinline__ float row16_sum(float x){
  x += __uint_as_float(__builtin_amdgcn_update_dpp(0, __float_as_uint(x), 0xB1,  0xf, 0xf, true));
  x += __uint_as_float(__builtin_amdgcn_update_dpp(0, __float_as_uint(x), 0x4E,  0xf, 0xf, true));
  x += __uint_as_float(__builtin_amdgcn_update_dpp(0, __float_as_uint(x), 0x141, 0xf, 0xf, true));
  x += __uint_as_float(__builtin_amdgcn_update_dpp(0, __float_as_uint(x), 0x140, 0xf, 0xf, true));
  return x;
}
__device__ __forceinline__ float hdot2(h16x2 a, h16x2 b){
#if __has_builtin(__builtin_amdgcn_fdot2)
  return __builtin_amdgcn_fdot2(a, b, 0.f, false);
#else
  return (float)a.x*(float)b.x + (float)a.y*(float)b.y;
#endif
}

// ============================ CSR build: single scatter, fixed capacity ============================
// Slot allocation via atomicAdd(deg) -> record at node*DEGCAP + slot.
// Replaces hist + 3-dispatch prefix-sum + scatter (5 dispatches -> 1).
__global__ void scatter_kernel(const int* __restrict__ src, const int* __restrict__ dst,
                               const float* __restrict__ ea, int* __restrict__ deg,
                               int2* __restrict__ csr){
  int e = blockIdx.x*blockDim.x + threadIdx.x;
  if(e >= NEDGES) return;
  int d = dst[e];
  int p = atomicAdd(&deg[d], 1);
  h16x2 eh; eh.x = (h16)ea[2*e]; eh.y = (h16)ea[2*e+1];
  csr[(size_t)d*DEGCAP + p] = make_int2(src[e], __builtin_bit_cast(int, eh));
}

// ============================ conv0 linear (K=4), f16 outputs ============================
__global__ void gemm_k4_dual(const float* __restrict__ x,
                             const float* __restrict__ Wa, const float* __restrict__ ba,
                             const float* __restrict__ Wb, const float* __restrict__ bb,
                             h16* __restrict__ outa, h16* __restrict__ outb){
  int idx = blockIdx.x*blockDim.x + threadIdx.x;
  if(idx >= NNODES*128) return;
  int r = idx >> 7, c = idx & 127;
  float4 xv = *(const float4*)&x[r*4];
  float acca = ba[c] + xv.x*Wa[c] + xv.y*Wa[128+c] + xv.z*Wa[256+c] + xv.w*Wa[384+c];
  float accb = bb[c] + xv.x*Wb[c] + xv.y*Wb[128+c] + xv.z*Wb[256+c] + xv.w*Wb[384+c];
  outa[idx] = (h16)acca;
  outb[idx] = (h16)accb;
}

// ============================ W prep: f16 + MFMA B-frag swizzle ============================
__global__ void wprep(const float* __restrict__ Wl, const float* __restrict__ Wr,
                      h16* __restrict__ Bh){
  int idx = blockIdx.x*256 + threadIdx.x;   // 8 layers * 2 mats * 32 frags * 64 lanes = 32768
  int lane  = idx & 63;
  int f     = (idx >> 6) & 31;
  int mat   = (idx >> 11) & 1;
  int layer = idx >> 12;
  int ct = f >> 2, ks = f & 3;
  const float* W = (mat ? Wr : Wl) + (size_t)layer*16384;
  int krow = ks*32 + (lane>>4)*8;
  int col  = ct*16 + (lane&15);
  size_t base = ((size_t)(layer*2 + mat)*32 + f)*512 + lane*8;
  #pragma unroll
  for(int j=0;j<8;j++){
    Bh[base+j] = (h16)W[(krow+j)*128 + col];
  }
}

// ============================ dual GEMM via MFMA (f16) ============================
__launch_bounds__(256)
__global__ void gemm_mfma(const h16* __restrict__ xh,
                          const h16* __restrict__ Bh,
                          const float* __restrict__ ba, const float* __restrict__ bb,
                          h16* __restrict__ outa, h16* __restrict__ outb){
  int tid = threadIdx.x;
  int lane = tid & 63;
  int gw = blockIdx.x*4 + (tid>>6);     // global wave id, 0..4095
  int cg = gw & 3;                      // col group: cols [cg*32, cg*32+32)
  int slab0 = gw >> 2;                  // 0..1023
  int m = lane & 15, quad = lane >> 4;

  h16x8 Bf[2][2][4];                    // [mat][c][ks]
  #pragma unroll
  for(int mat=0;mat<2;mat++)
    #pragma unroll
    for(int c=0;c<2;c++)
      #pragma unroll
      for(int ks=0;ks<4;ks++){
        size_t o = ((size_t)mat*32 + (size_t)(cg*2+c)*4 + ks)*512 + lane*8;
        Bf[mat][c][ks] = *(const h16x8*)&Bh[o];
      }
  float bav[2] = { ba[cg*32 + m], ba[cg*32 + 16 + m] };
  float bbv[2] = { bb[cg*32 + m], bb[cg*32 + 16 + m] };

  for(int slab = slab0; slab < NSLABS; slab += 1024){
    int row0 = slab*16;
    const h16* pa = xh + (size_t)(row0+m)*128 + quad*8;
    f32x4 acc[2][2];
    #pragma unroll
    for(int mat=0;mat<2;mat++)
      #pragma unroll
      for(int c=0;c<2;c++) acc[mat][c] = (f32x4){0.f,0.f,0.f,0.f};
    #pragma unroll
    for(int ks=0;ks<4;ks++){
      h16x8 Ah = *(const h16x8*)(pa + ks*32);
      #pragma unroll
      for(int mat=0;mat<2;mat++)
        #pragma unroll
        for(int c=0;c<2;c++)
          acc[mat][c] = __builtin_amdgcn_mfma_f32_16x16x32_f16(Ah, Bf[mat][c][ks], acc[mat][c], 0,0,0);
    }
    #pragma unroll
    for(int c=0;c<2;c++){
      int col = cg*32 + c*16 + m;
      #pragma unroll
      for(int r=0;r<4;r++){
        int row = row0 + quad*4 + r;
        outa[(size_t)row*128 + col] = (h16)(acc[0][c][r] + bav[c]);
        outb[(size_t)row*128 + col] = (h16)(acc[1][c][r] + bbv[c]);
      }
    }
  }
}

// ============================ fused GATv2 edge phase ============================
// Block = 64 (1 wave/node — granularity-monotone winner). Packed-f16 logit
// math, DPP row reductions, 8B CSR records at fixed base node*DEGCAP
// (single deg load instead of two off loads), log2-domain softmax, ILP=4.
__launch_bounds__(64)
__global__ void edge_kernel(const h16* __restrict__ xlb, const h16* __restrict__ xrb,
                            const int* __restrict__ deg, const int2* __restrict__ csr,
                            const float* __restrict__ We, const float* __restrict__ att,
                            const float* __restrict__ bias, const h16* __restrict__ res_h,
                            h16* __restrict__ out_h){
  int wid  = blockIdx.x;                // one node per block (= one wave)
  int lane = threadIdx.x;
  if(wid >= NNODES) return;
  int node = __builtin_amdgcn_readfirstlane(wid);
  int c0 = lane*2;
  const float LOG2E = 1.44269504f;
  h16x2 avh; avh.x = (h16)(att[c0]*LOG2E); avh.y = (h16)(att[c0+1]*LOG2E);
  h16x2 w0h; w0h.x = (h16)We[c0];       w0h.y = (h16)We[c0+1];
  h16x2 w1h; w1h.x = (h16)We[128+c0];   w1h.y = (h16)We[128+c0+1];
  h16x2 xr2h = u2h(*(const unsigned*)&xrb[node*128 + c0]);
  h16x2 xlsh = u2h(*(const unsigned*)&xlb[node*128 + c0]);
  f32x2 xls = (f32x2){(float)xlsh.x, (float)xlsh.y};

  // self-loop logit (src=node, ea=0) -> reference m0 (log2 domain)
  h16x2 z0 = xlsh + xr2h;
  h16x2 z0s = z0 * (h16)0.2f;
  h16x2 z0m = __builtin_elementwise_max(z0, z0s);
  float m0 = row16_sum(hdot2(z0m, avh));
  float den = 1.f;
  f32x2 acc = xls;

  int ecnt = deg[node];                 // scalar (via readfirstlane base)
  const int2* crow = csr + (size_t)node*DEGCAP;
  for(int e=0; e<ecnt; e+=4){
    int cnt = ecnt - e;                 // scalar
    int   s[4];
    h16x2 eah[4];
    #pragma unroll
    for(int j=0;j<4;j++){
      if(j < cnt){
        int2 rec = crow[e+j];           // broadcast 8B load
        s[j] = __builtin_amdgcn_readfirstlane(rec.x);
        eah[j] = u2h((unsigned)rec.y);
      } else {
        s[j] = node; eah[j] = (h16x2){(h16)0.f,(h16)0.f};
      }
    }
    h16x2 xvh[4];
    #pragma unroll
    for(int j=0;j<4;j++) xvh[j] = u2h(*(const unsigned*)&xlb[(size_t)s[j]*128 + c0]);
    float p[4];
    #pragma unroll
    for(int j=0;j<4;j++){
      h16x2 ax = (h16x2){eah[j].x, eah[j].x};
      h16x2 ay = (h16x2){eah[j].y, eah[j].y};
      h16x2 t = xvh[j] + xr2h;
      t = t + ax*w0h;
      t = t + ay*w1h;
      h16x2 ts = t * (h16)0.2f;
      h16x2 tm = __builtin_elementwise_max(t, ts);
      p[j] = row16_sum(hdot2(tm, avh));               // log2 domain
    }
    #pragma unroll
    for(int j=0;j<4;j++) if(j >= cnt) p[j] = -1e30f;
    float pe[4];
    #pragma unroll
    for(int j=0;j<4;j++) pe[j] = __builtin_amdgcn_exp2f(p[j] - m0);
    den += (pe[0]+pe[1]) + (pe[2]+pe[3]);
    #pragma unroll
    for(int j=0;j<4;j++){
      f32x2 xv = (f32x2){(float)xvh[j].x, (float)xvh[j].y};
      acc = acc + pe[j]*xv;
    }
  }
  float inv = 1.f/den;                  // den >= 1
  float ox = acc.x*inv + bias[c0];
  float oy = acc.y*inv + bias[c0+1];
  ox = ox > 0.f ? ox : 0.f;
  oy = oy > 0.f ? oy : 0.f;
  if(res_h){
    f32x2 rv = hpair(*(const unsigned*)&res_h[node*128 + c0]);
    ox += rv.x; oy += rv.y;
  }
  h16x2 oh; oh.x = (h16)ox; oh.y = (h16)oy;
  *(h16x2*)&out_h[node*128 + c0] = oh;
}

// ============================ pooling (f16 input) ============================
#define POOL_CHUNK 128
__launch_bounds__(128)
__global__ void pool_kernel(const h16* __restrict__ x, const int* __restrict__ batch,
                            float* __restrict__ sums, float* __restrict__ maxv,
                            float* __restrict__ cnt){
  int c = threadIdx.x;
  int n0 = blockIdx.x * POOL_CHUNK;
  if(n0 >= NNODES) return;
  int n1 = n0 + POOL_CHUNK; if(n1 > NNODES) n1 = NNODES;
  int curb = batch[n0];
  float s = 0.f, mx = 0.f;
  float segc = 0.f;
  for(int nd = n0; nd < n1; nd++){
    int b = batch[nd];
    if(b != curb){
      atomicAdd(&sums[curb*128 + c], s);
      atomicMax((int*)&maxv[curb*128 + c], __float_as_int(mx));
      if(c == 0) atomicAdd(&cnt[curb], segc);
      curb = b; s = 0.f; mx = 0.f; segc = 0.f;
    }
    float v = (float)x[nd*128 + c];
    s += v; mx = fmaxf(mx, v); segc += 1.f;
  }
  atomicAdd(&sums[curb*128 + c], s);
  atomicMax((int*)&maxv[curb*128 + c], __float_as_int(mx));
  if(c == 0) atomicAdd(&cnt[curb], segc);
}

// ============================ fused dense trunk + heads ============================
__launch_bounds__(128)
__global__ void fused_dense(const float* __restrict__ sums, const float* __restrict__ maxv,
                            const float* __restrict__ cnt,
                            const float* __restrict__ D1_W, const float* __restrict__ D1_b,
                            const float* __restrict__ D23_W, const float* __restrict__ D23_b,
                            const float* __restrict__ H1_W, const float* __restrict__ H1_b,
                            const float* __restrict__ H2_W, const float* __restrict__ H2_b,
                            const float* __restrict__ H3_W, const float* __restrict__ H3_b,
                            float* __restrict__ out){
  __shared__ float X[256];
  __shared__ float y[128];
  __shared__ float z[128];
  int b = blockIdx.x, h = blockIdx.y, t = threadIdx.x;
  float ct = cnt[b]; ct = ct > 1.f ? ct : 1.f;
  X[t]       = sums[b*128 + t] / ct;
  X[128 + t] = maxv[b*128 + t];
  __syncthreads();
  float acc = D1_b[t];
  #pragma unroll 16
  for(int k=0;k<256;k++) acc += X[k]*D1_W[k*128+t];
  y[t] = fmaxf(acc, 0.f);
  __syncthreads();
  acc = D23_b[t];
  #pragma unroll 16
  for(int k=0;k<128;k++) acc += y[k]*D23_W[k*128+t];
  z[t] = fmaxf(acc, 0.f);
  __syncthreads();
  acc = D23_b[128+t];
  #pragma unroll 16
  for(int k=0;k<128;k++) acc += z[k]*D23_W[16384 + k*128+t];
  y[t] = fmaxf(acc, 0.f);
  __syncthreads();
  acc = H1_b[h*128+t];
  #pragma unroll 16
  for(int k=0;k<128;k++) acc += y[k]*H1_W[h*16384 + k*128+t];
  z[t] = fmaxf(acc, 0.f);
  __syncthreads();
  float v = 0.f;
  if(t < 64){
    float a2 = H2_b[h*64+t];
    #pragma unroll 16
    for(int k=0;k<128;k++) a2 += z[k]*H2_W[h*8192 + k*64+t];
    a2 = fmaxf(a2, 0.f);
    v = a2 * H3_W[h*64 + t];
  }
  #pragma unroll
  for(int o=1;o<64;o<<=1) v += __shfl_xor(v, o, 64);
  if(t == 0){
    float r = v + H3_b[h];
    if(h == 0) r = tanhf(r);
    out[b*3 + h] = r;
  }
}

// ============================ launch ============================
extern "C" void kernel_launch(void* const* d_in, const int* in_sizes, int n_in,
                              void* d_out, int out_size, void* d_ws, size_t ws_size,
                              hipStream_t stream) {
  const float* nodes  = (const float*)d_in[0];
  const int*   eidx   = (const int*)  d_in[1];
  const float* eattr  = (const float*)d_in[2];
  const int*   batch  = (const int*)  d_in[3];
  const float* W0l    = (const float*)d_in[4];
  const float* b0l    = (const float*)d_in[5];
  const float* W0r    = (const float*)d_in[6];
  const float* b0r    = (const float*)d_in[7];
  const float* W0e    = (const float*)d_in[8];
  const float* att0   = (const float*)d_in[9];
  const float* bias0  = (const float*)d_in[10];
  const float* Wl     = (const float*)d_in[11];
  const float* bl     = (const float*)d_in[12];
  const float* Wr     = (const float*)d_in[13];
  const float* br     = (const float*)d_in[14];
  const float* We     = (const float*)d_in[15];
  const float* atts   = (const float*)d_in[16];
  const float* biases = (const float*)d_in[17];
  const float* D1_W   = (const float*)d_in[18];
  const float* D1_b   = (const float*)d_in[19];
  const float* D23_W  = (const float*)d_in[20];
  const float* D23_b  = (const float*)d_in[21];
  const float* H1_W   = (const float*)d_in[22];
  const float* H1_b   = (const float*)d_in[23];
  const float* H2_W   = (const float*)d_in[24];
  const float* H2_b   = (const float*)d_in[25];
  const float* H3_W   = (const float*)d_in[26];
  const float* H3_b   = (const float*)d_in[27];

  // ---- workspace layout (deg and pool adjacent -> single memset) ----
  char* ws = (char*)d_ws;
  size_t o = 0;
  auto alloc = [&](size_t bytes)->char*{ char* p = ws + o; o = (o + bytes + 255) & ~(size_t)255; return p; };
  int*    deg     = (int*)   alloc(NNODES*4 + (NBATCH*128*2 + NBATCH)*4);  // deg + pool block
  float*  pool    = (float*)(deg + NNODES);
  float*  sums    = pool;
  float*  maxv    = pool + NBATCH*128;
  float*  cnt     = pool + NBATCH*256;
  int2*   csr     = (int2*)  alloc((size_t)NNODES*DEGCAP*8);  // fixed-capacity CSR
  h16*    xlb     = (h16*)   alloc((size_t)NNODES*128*2);     // f16 xl (gather target)
  h16*    xrb     = (h16*)   alloc((size_t)NNODES*128*2);     // f16 xr (logits only)
  h16*    bufA    = (h16*)   alloc((size_t)NNODES*128*2);     // block in/out + residual + pool input
  h16*    bufB    = (h16*)   alloc((size_t)NNODES*128*2);
  h16*    Bh      = (h16*)   alloc((size_t)8*2*32*512*2);     // swizzled W (f16)
  (void)ws_size; (void)in_sizes; (void)n_in; (void)out_size;

  const int* src = eidx;
  const int* dst = eidx + NEDGES;

  // ---- CSR build (single scatter) + W prep ----
  hipMemsetAsync(deg, 0, NNODES*4 + (NBATCH*128*2 + NBATCH)*4, stream);
  scatter_kernel<<<(NEDGES+255)/256, 256, 0, stream>>>(src, dst, eattr, deg, csr);
  wprep<<<128, 256, 0, stream>>>(Wl, Wr, Bh);

  // ---- conv0 ----
  gemm_k4_dual<<<(NNODES*128+255)/256, 256, 0, stream>>>(nodes, W0l, b0l, W0r, b0r, xlb, xrb);
  edge_kernel<<<NNODES, 64, 0, stream>>>(xlb, xrb, deg, csr,
                                         W0e, att0, bias0, nullptr, bufA);

  // ---- 4 skip blocks x 2 convs ----
  const size_t wstride = (size_t)2*32*512;   // per-layer stride in swizzled W
  for(int blk=0; blk<4; blk++){
    int j = 2*blk;
    gemm_mfma<<<1024, 256, 0, stream>>>(bufA, Bh + (size_t)j*wstride,
                                        bl + j*128, br + j*128, xlb, xrb);
    edge_kernel<<<NNODES, 64, 0, stream>>>(xlb, xrb, deg, csr,
                                           We + j*256, atts + j*128, biases + j*128,
                                           nullptr, bufB);
    j = 2*blk + 1;
    gemm_mfma<<<1024, 256, 0, stream>>>(bufB, Bh + (size_t)j*wstride,
                                        bl + j*128, br + j*128, xlb, xrb);
    edge_kernel<<<NNODES, 64, 0, stream>>>(xlb, xrb, deg, csr,
                                           We + j*256, atts + j*128, biases + j*128,
                                           bufA, bufA);
  }

  // ---- pooling + fused dense trunk/heads ----
  pool_kernel<<<(NNODES + POOL_CHUNK - 1)/POOL_CHUNK, 128, 0, stream>>>(bufA, batch, sums, maxv, cnt);
  fused_dense<<<dim3(NBATCH,3), 128, 0, stream>>>(sums, maxv, cnt,
                                          D1_W, D1_b, D23_W, D23_b,
                                          H1_W, H1_b, H2_W, H2_b, H3_W, H3_b,
                                          (float*)d_out);
}

// Round 24
// 735.921 us; speedup vs baseline: 1.0104x; 1.0104x over previous
//
#include <hip/hip_runtime.h>
#include <hip/hip_bf16.h>
#include <cmath>

#define NNODES 50000
#define NEDGES 600000
#define NBATCH 50
#define SCAN_BLOCK 256
#define NCHUNK ((NNODES + SCAN_BLOCK - 1) / SCAN_BLOCK)   // 196
#define NSLABS (NNODES/16)                                // 3125 (exact)

typedef _Float16 h16;
typedef __attribute__((ext_vector_type(2))) _Float16 h16x2;
typedef __attribute__((ext_vector_type(8))) _Float16 h16x8;
typedef __attribute__((ext_vector_type(4))) float f32x4;
typedef __attribute__((ext_vector_type(2))) float f32x2;

__device__ __forceinline__ h16x2 u2h(unsigned u){ return __builtin_bit_cast(h16x2, u); }
__device__ __forceinline__ f32x2 hpair(unsigned u){
  h16x2 h = u2h(u);
  return (f32x2){(float)h.x, (float)h.y};
}
// 16-lane-row sum via DPP (no LDS pipe): quad_perm xor1, xor2, half_mirror, mirror.
__device__ __forceinline__ float row16_sum(float x){
  x += __uint_as_float(__builtin_amdgcn_update_dpp(0, __float_as_uint(x), 0xB1,  0xf, 0xf, true));
  x += __uint_as_float(__builtin_amdgcn_update_dpp(0, __float_as_uint(x), 0x4E,  0xf, 0xf, true));
  x += __uint_as_float(__builtin_amdgcn_update_dpp(0, __float_as_uint(x), 0x141, 0xf, 0xf, true));
  x += __uint_as_float(__builtin_amdgcn_update_dpp(0, __float_as_uint(x), 0x140, 0xf, 0xf, true));
  return x;
}
__device__ __forceinline__ float hdot2(h16x2 a, h16x2 b){
#if __has_builtin(__builtin_amdgcn_fdot2)
  return __builtin_amdgcn_fdot2(a, b, 0.f, false);
#else
  return (float)a.x*(float)b.x + (float)a.y*(float)b.y;
#endif
}

// ============================ CSR build (compact layout — cache-dense) ============================
__global__ void hist_kernel(const int* __restrict__ dst, int* __restrict__ deg){
  int e = blockIdx.x*blockDim.x + threadIdx.x;
  if(e < NEDGES) atomicAdd(&deg[dst[e]], 1);
}

__global__ void deg_partial(const int* __restrict__ deg, int* __restrict__ part){
  __shared__ int red[SCAN_BLOCK];
  int t = threadIdx.x, id = blockIdx.x*SCAN_BLOCK + t;
  red[t] = (id < NNODES) ? deg[id] : 0;
  __syncthreads();
  for(int o = SCAN_BLOCK/2; o > 0; o >>= 1){
    if(t < o) red[t] += red[t+o];
    __syncthreads();
  }
  if(t == 0) part[blockIdx.x] = red[0];
}

__global__ void part_scan(int* __restrict__ part){
  __shared__ int ps[256];
  int t = threadIdx.x;
  int v = (t < NCHUNK) ? part[t] : 0;
  ps[t] = v; __syncthreads();
  for(int o=1;o<256;o<<=1){
    int u = (t>=o) ? ps[t-o] : 0;
    __syncthreads();
    ps[t] += u;
    __syncthreads();
  }
  if(t < NCHUNK) part[t] = ps[t] - v;   // exclusive
}

__global__ void scan_final(const int* __restrict__ deg, const int* __restrict__ part,
                           int* __restrict__ off, int* __restrict__ cur){
  __shared__ int ps[SCAN_BLOCK];
  int t = threadIdx.x, id = blockIdx.x*SCAN_BLOCK + t;
  int v = (id < NNODES) ? deg[id] : 0;
  ps[t] = v; __syncthreads();
  for(int o=1;o<SCAN_BLOCK;o<<=1){
    int u = (t>=o) ? ps[t-o] : 0;
    __syncthreads();
    ps[t] += u;
    __syncthreads();
  }
  int excl = ps[t] - v + part[blockIdx.x];
  if(id < NNODES){ off[id] = excl; cur[id] = excl; }
  if(id == 0) off[NNODES] = NEDGES;
}

// one interleaved 8B record per edge: (src, packed f16 ea pair)
__global__ void scatter_kernel(const int* __restrict__ src, const int* __restrict__ dst,
                               const float* __restrict__ ea, int* __restrict__ cur,
                               int2* __restrict__ csr){
  int e = blockIdx.x*blockDim.x + threadIdx.x;
  if(e >= NEDGES) return;
  int d = dst[e];
  int p = atomicAdd(&cur[d], 1);
  h16x2 eh; eh.x = (h16)ea[2*e]; eh.y = (h16)ea[2*e+1];
  csr[p] = make_int2(src[e], __builtin_bit_cast(int, eh));
}

// ============================ conv0 linear (K=4), f16 outputs ============================
__global__ void gemm_k4_dual(const float* __restrict__ x,
                             const float* __restrict__ Wa, const float* __restrict__ ba,
                             const float* __restrict__ Wb, const float* __restrict__ bb,
                             h16* __restrict__ outa, h16* __restrict__ outb){
  int idx = blockIdx.x*blockDim.x + threadIdx.x;
  if(idx >= NNODES*128) return;
  int r = idx >> 7, c = idx & 127;
  float4 xv = *(const float4*)&x[r*4];
  float acca = ba[c] + xv.x*Wa[c] + xv.y*Wa[128+c] + xv.z*Wa[256+c] + xv.w*Wa[384+c];
  float accb = bb[c] + xv.x*Wb[c] + xv.y*Wb[128+c] + xv.z*Wb[256+c] + xv.w*Wb[384+c];
  outa[idx] = (h16)acca;
  outb[idx] = (h16)accb;
}

// ============================ W prep: f16 + MFMA B-frag swizzle ============================
__global__ void wprep(const float* __restrict__ Wl, const float* __restrict__ Wr,
                      h16* __restrict__ Bh){
  int idx = blockIdx.x*256 + threadIdx.x;   // 8 layers * 2 mats * 32 frags * 64 lanes = 32768
  int lane  = idx & 63;
  int f     = (idx >> 6) & 31;
  int mat   = (idx >> 11) & 1;
  int layer = idx >> 12;
  int ct = f >> 2, ks = f & 3;
  const float* W = (mat ? Wr : Wl) + (size_t)layer*16384;
  int krow = ks*32 + (lane>>4)*8;
  int col  = ct*16 + (lane&15);
  size_t base = ((size_t)(layer*2 + mat)*32 + f)*512 + lane*8;
  #pragma unroll
  for(int j=0;j<8;j++){
    Bh[base+j] = (h16)W[(krow+j)*128 + col];
  }
}

// ============================ dual GEMM via MFMA (f16) ============================
__launch_bounds__(256)
__global__ void gemm_mfma(const h16* __restrict__ xh,
                          const h16* __restrict__ Bh,
                          const float* __restrict__ ba, const float* __restrict__ bb,
                          h16* __restrict__ outa, h16* __restrict__ outb){
  int tid = threadIdx.x;
  int lane = tid & 63;
  int gw = blockIdx.x*4 + (tid>>6);     // global wave id, 0..4095
  int cg = gw & 3;                      // col group: cols [cg*32, cg*32+32)
  int slab0 = gw >> 2;                  // 0..1023
  int m = lane & 15, quad = lane >> 4;

  h16x8 Bf[2][2][4];                    // [mat][c][ks]
  #pragma unroll
  for(int mat=0;mat<2;mat++)
    #pragma unroll
    for(int c=0;c<2;c++)
      #pragma unroll
      for(int ks=0;ks<4;ks++){
        size_t o = ((size_t)mat*32 + (size_t)(cg*2+c)*4 + ks)*512 + lane*8;
        Bf[mat][c][ks] = *(const h16x8*)&Bh[o];
      }
  float bav[2] = { ba[cg*32 + m], ba[cg*32 + 16 + m] };
  float bbv[2] = { bb[cg*32 + m], bb[cg*32 + 16 + m] };

  for(int slab = slab0; slab < NSLABS; slab += 1024){
    int row0 = slab*16;
    const h16* pa = xh + (size_t)(row0+m)*128 + quad*8;
    f32x4 acc[2][2];
    #pragma unroll
    for(int mat=0;mat<2;mat++)
      #pragma unroll
      for(int c=0;c<2;c++) acc[mat][c] = (f32x4){0.f,0.f,0.f,0.f};
    #pragma unroll
    for(int ks=0;ks<4;ks++){
      h16x8 Ah = *(const h16x8*)(pa + ks*32);
      #pragma unroll
      for(int mat=0;mat<2;mat++)
        #pragma unroll
        for(int c=0;c<2;c++)
          acc[mat][c] = __builtin_amdgcn_mfma_f32_16x16x32_f16(Ah, Bf[mat][c][ks], acc[mat][c], 0,0,0);
    }
    #pragma unroll
    for(int c=0;c<2;c++){
      int col = cg*32 + c*16 + m;
      #pragma unroll
      for(int r=0;r<4;r++){
        int row = row0 + quad*4 + r;
        outa[(size_t)row*128 + col] = (h16)(acc[0][c][r] + bav[c]);
        outb[(size_t)row*128 + col] = (h16)(acc[1][c][r] + bbv[c]);
      }
    }
  }
}

// ============================ fused GATv2 edge phase ============================
// Block = 64 (1 wave/node — granularity-monotone winner). Packed-f16 logit
// math, DPP row reductions, compact 8B CSR records (cache-dense — the
// fixed-capacity strided layout REGRESSED edge 44.4->47.8 us),
// log2-domain softmax, ILP=4, scalar indices via readfirstlane.
__launch_bounds__(64)
__global__ void edge_kernel(const h16* __restrict__ xlb, const h16* __restrict__ xrb,
                            const int* __restrict__ off, const int2* __restrict__ csr,
                            const float* __restrict__ We, const float* __restrict__ att,
                            const float* __restrict__ bias, const h16* __restrict__ res_h,
                            h16* __restrict__ out_h){
  int wid  = blockIdx.x;                // one node per block (= one wave)
  int lane = threadIdx.x;
  if(wid >= NNODES) return;
  int node = __builtin_amdgcn_readfirstlane(wid);
  int c0 = lane*2;
  const float LOG2E = 1.44269504f;
  h16x2 avh; avh.x = (h16)(att[c0]*LOG2E); avh.y = (h16)(att[c0+1]*LOG2E);
  h16x2 w0h; w0h.x = (h16)We[c0];       w0h.y = (h16)We[c0+1];
  h16x2 w1h; w1h.x = (h16)We[128+c0];   w1h.y = (h16)We[128+c0+1];
  h16x2 xr2h = u2h(*(const unsigned*)&xrb[node*128 + c0]);
  h16x2 xlsh = u2h(*(const unsigned*)&xlb[node*128 + c0]);
  f32x2 xls = (f32x2){(float)xlsh.x, (float)xlsh.y};

  // self-loop logit (src=node, ea=0) -> reference m0 (log2 domain)
  h16x2 z0 = xlsh + xr2h;
  h16x2 z0s = z0 * (h16)0.2f;
  h16x2 z0m = __builtin_elementwise_max(z0, z0s);
  float m0 = row16_sum(hdot2(z0m, avh));
  float den = 1.f;
  f32x2 acc = xls;

  int e0 = off[node], e1 = off[node+1];
  for(int e=e0; e<e1; e+=4){
    int cnt = e1 - e;                   // scalar
    int   s[4];
    h16x2 eah[4];
    #pragma unroll
    for(int j=0;j<4;j++){
      if(j < cnt){
        int2 rec = csr[e+j];            // broadcast 8B load
        s[j] = __builtin_amdgcn_readfirstlane(rec.x);
        eah[j] = u2h((unsigned)rec.y);
      } else {
        s[j] = node; eah[j] = (h16x2){(h16)0.f,(h16)0.f};
      }
    }
    h16x2 xvh[4];
    #pragma unroll
    for(int j=0;j<4;j++) xvh[j] = u2h(*(const unsigned*)&xlb[(size_t)s[j]*128 + c0]);
    float p[4];
    #pragma unroll
    for(int j=0;j<4;j++){
      h16x2 ax = (h16x2){eah[j].x, eah[j].x};
      h16x2 ay = (h16x2){eah[j].y, eah[j].y};
      h16x2 t = xvh[j] + xr2h;
      t = t + ax*w0h;
      t = t + ay*w1h;
      h16x2 ts = t * (h16)0.2f;
      h16x2 tm = __builtin_elementwise_max(t, ts);
      p[j] = row16_sum(hdot2(tm, avh));               // log2 domain
    }
    #pragma unroll
    for(int j=0;j<4;j++) if(j >= cnt) p[j] = -1e30f;
    float pe[4];
    #pragma unroll
    for(int j=0;j<4;j++) pe[j] = __builtin_amdgcn_exp2f(p[j] - m0);
    den += (pe[0]+pe[1]) + (pe[2]+pe[3]);
    #pragma unroll
    for(int j=0;j<4;j++){
      f32x2 xv = (f32x2){(float)xvh[j].x, (float)xvh[j].y};
      acc = acc + pe[j]*xv;
    }
  }
  float inv = 1.f/den;                  // den >= 1
  float ox = acc.x*inv + bias[c0];
  float oy = acc.y*inv + bias[c0+1];
  ox = ox > 0.f ? ox : 0.f;
  oy = oy > 0.f ? oy : 0.f;
  if(res_h){
    f32x2 rv = hpair(*(const unsigned*)&res_h[node*128 + c0]);
    ox += rv.x; oy += rv.y;
  }
  h16x2 oh; oh.x = (h16)ox; oh.y = (h16)oy;
  *(h16x2*)&out_h[node*128 + c0] = oh;
}

// ============================ pooling (f16 input) ============================
#define POOL_CHUNK 128
__launch_bounds__(128)
__global__ void pool_kernel(const h16* __restrict__ x, const int* __restrict__ batch,
                            float* __restrict__ sums, float* __restrict__ maxv,
                            float* __restrict__ cnt){
  int c = threadIdx.x;
  int n0 = blockIdx.x * POOL_CHUNK;
  if(n0 >= NNODES) return;
  int n1 = n0 + POOL_CHUNK; if(n1 > NNODES) n1 = NNODES;
  int curb = batch[n0];
  float s = 0.f, mx = 0.f;
  float segc = 0.f;
  for(int nd = n0; nd < n1; nd++){
    int b = batch[nd];
    if(b != curb){
      atomicAdd(&sums[curb*128 + c], s);
      atomicMax((int*)&maxv[curb*128 + c], __float_as_int(mx));
      if(c == 0) atomicAdd(&cnt[curb], segc);
      curb = b; s = 0.f; mx = 0.f; segc = 0.f;
    }
    float v = (float)x[nd*128 + c];
    s += v; mx = fmaxf(mx, v); segc += 1.f;
  }
  atomicAdd(&sums[curb*128 + c], s);
  atomicMax((int*)&maxv[curb*128 + c], __float_as_int(mx));
  if(c == 0) atomicAdd(&cnt[curb], segc);
}

// ============================ fused dense trunk + heads ============================
__launch_bounds__(128)
__global__ void fused_dense(const float* __restrict__ sums, const float* __restrict__ maxv,
                            const float* __restrict__ cnt,
                            const float* __restrict__ D1_W, const float* __restrict__ D1_b,
                            const float* __restrict__ D23_W, const float* __restrict__ D23_b,
                            const float* __restrict__ H1_W, const float* __restrict__ H1_b,
                            const float* __restrict__ H2_W, const float* __restrict__ H2_b,
                            const float* __restrict__ H3_W, const float* __restrict__ H3_b,
                            float* __restrict__ out){
  __shared__ float X[256];
  __shared__ float y[128];
  __shared__ float z[128];
  int b = blockIdx.x, h = blockIdx.y, t = threadIdx.x;
  float ct = cnt[b]; ct = ct > 1.f ? ct : 1.f;
  X[t]       = sums[b*128 + t] / ct;
  X[128 + t] = maxv[b*128 + t];
  __syncthreads();
  float acc = D1_b[t];
  #pragma unroll 16
  for(int k=0;k<256;k++) acc += X[k]*D1_W[k*128+t];
  y[t] = fmaxf(acc, 0.f);
  __syncthreads();
  acc = D23_b[t];
  #pragma unroll 16
  for(int k=0;k<128;k++) acc += y[k]*D23_W[k*128+t];
  z[t] = fmaxf(acc, 0.f);
  __syncthreads();
  acc = D23_b[128+t];
  #pragma unroll 16
  for(int k=0;k<128;k++) acc += z[k]*D23_W[16384 + k*128+t];
  y[t] = fmaxf(acc, 0.f);
  __syncthreads();
  acc = H1_b[h*128+t];
  #pragma unroll 16
  for(int k=0;k<128;k++) acc += y[k]*H1_W[h*16384 + k*128+t];
  z[t] = fmaxf(acc, 0.f);
  __syncthreads();
  float v = 0.f;
  if(t < 64){
    float a2 = H2_b[h*64+t];
    #pragma unroll 16
    for(int k=0;k<128;k++) a2 += z[k]*H2_W[h*8192 + k*64+t];
    a2 = fmaxf(a2, 0.f);
    v = a2 * H3_W[h*64 + t];
  }
  #pragma unroll
  for(int o=1;o<64;o<<=1) v += __shfl_xor(v, o, 64);
  if(t == 0){
    float r = v + H3_b[h];
    if(h == 0) r = tanhf(r);
    out[b*3 + h] = r;
  }
}

// ============================ launch ============================
extern "C" void kernel_launch(void* const* d_in, const int* in_sizes, int n_in,
                              void* d_out, int out_size, void* d_ws, size_t ws_size,
                              hipStream_t stream) {
  const float* nodes  = (const float*)d_in[0];
  const int*   eidx   = (const int*)  d_in[1];
  const float* eattr  = (const float*)d_in[2];
  const int*   batch  = (const int*)  d_in[3];
  const float* W0l    = (const float*)d_in[4];
  const float* b0l    = (const float*)d_in[5];
  const float* W0r    = (const float*)d_in[6];
  const float* b0r    = (const float*)d_in[7];
  const float* W0e    = (const float*)d_in[8];
  const float* att0   = (const float*)d_in[9];
  const float* bias0  = (const float*)d_in[10];
  const float* Wl     = (const float*)d_in[11];
  const float* bl     = (const float*)d_in[12];
  const float* Wr     = (const float*)d_in[13];
  const float* br     = (const float*)d_in[14];
  const float* We     = (const float*)d_in[15];
  const float* atts   = (const float*)d_in[16];
  const float* biases = (const float*)d_in[17];
  const float* D1_W   = (const float*)d_in[18];
  const float* D1_b   = (const float*)d_in[19];
  const float* D23_W  = (const float*)d_in[20];
  const float* D23_b  = (const float*)d_in[21];
  const float* H1_W   = (const float*)d_in[22];
  const float* H1_b   = (const float*)d_in[23];
  const float* H2_W   = (const float*)d_in[24];
  const float* H2_b   = (const float*)d_in[25];
  const float* H3_W   = (const float*)d_in[26];
  const float* H3_b   = (const float*)d_in[27];

  // ---- workspace layout (deg and pool adjacent -> single memset) ----
  char* ws = (char*)d_ws;
  size_t o = 0;
  auto alloc = [&](size_t bytes)->char*{ char* p = ws + o; o = (o + bytes + 255) & ~(size_t)255; return p; };
  int*    deg     = (int*)   alloc(NNODES*4 + (NBATCH*128*2 + NBATCH)*4);  // deg + pool block
  float*  pool    = (float*)(deg + NNODES);
  float*  sums    = pool;
  float*  maxv    = pool + NBATCH*128;
  float*  cnt     = pool + NBATCH*256;
  int*    offs    = (int*)   alloc((NNODES+1)*4);
  int*    cur     = (int*)   alloc(NNODES*4);
  int*    part    = (int*)   alloc(NCHUNK*4);
  int2*   csr     = (int2*)  alloc((size_t)NEDGES*8);
  h16*    xlb     = (h16*)   alloc((size_t)NNODES*128*2);   // f16 xl (gather target)
  h16*    xrb     = (h16*)   alloc((size_t)NNODES*128*2);   // f16 xr (logits only)
  h16*    bufA    = (h16*)   alloc((size_t)NNODES*128*2);   // block in/out + residual + pool input
  h16*    bufB    = (h16*)   alloc((size_t)NNODES*128*2);
  h16*    Bh      = (h16*)   alloc((size_t)8*2*32*512*2);   // swizzled W (f16)
  (void)ws_size; (void)in_sizes; (void)n_in; (void)out_size;

  const int* src = eidx;
  const int* dst = eidx + NEDGES;

  // ---- CSR build + W prep ----
  hipMemsetAsync(deg, 0, NNODES*4 + (NBATCH*128*2 + NBATCH)*4, stream);
  hist_kernel<<<(NEDGES+255)/256, 256, 0, stream>>>(dst, deg);
  deg_partial<<<NCHUNK, SCAN_BLOCK, 0, stream>>>(deg, part);
  part_scan<<<1, 256, 0, stream>>>(part);
  scan_final<<<NCHUNK, SCAN_BLOCK, 0, stream>>>(deg, part, offs, cur);
  scatter_kernel<<<(NEDGES+255)/256, 256, 0, stream>>>(src, dst, eattr, cur, csr);
  wprep<<<128, 256, 0, stream>>>(Wl, Wr, Bh);

  // ---- conv0 ----
  gemm_k4_dual<<<(NNODES*128+255)/256, 256, 0, stream>>>(nodes, W0l, b0l, W0r, b0r, xlb, xrb);
  edge_kernel<<<NNODES, 64, 0, stream>>>(xlb, xrb, offs, csr,
                                         W0e, att0, bias0, nullptr, bufA);

  // ---- 4 skip blocks x 2 convs ----
  const size_t wstride = (size_t)2*32*512;   // per-layer stride in swizzled W
  for(int blk=0; blk<4; blk++){
    int j = 2*blk;
    gemm_mfma<<<1024, 256, 0, stream>>>(bufA, Bh + (size_t)j*wstride,
                                        bl + j*128, br + j*128, xlb, xrb);
    edge_kernel<<<NNODES, 64, 0, stream>>>(xlb, xrb, offs, csr,
                                           We + j*256, atts + j*128, biases + j*128,
                                           nullptr, bufB);
    j = 2*blk + 1;
    gemm_mfma<<<1024, 256, 0, stream>>>(bufB, Bh + (size_t)j*wstride,
                                        bl + j*128, br + j*128, xlb, xrb);
    edge_kernel<<<NNODES, 64, 0, stream>>>(xlb, xrb, offs, csr,
                                           We + j*256, atts + j*128, biases + j*128,
                                           bufA, bufA);
  }

  // ---- pooling + fused dense trunk/heads ----
  pool_kernel<<<(NNODES + POOL_CHUNK - 1)/POOL_CHUNK, 128, 0, stream>>>(bufA, batch, sums, maxv, cnt);
  fused_dense<<<dim3(NBATCH,3), 128, 0, stream>>>(sums, maxv, cnt,
                                          D1_W, D1_b, D23_W, D23_b,
                                          H1_W, H1_b, H2_W, H2_b, H3_W, H3_b,
                                          (float*)d_out);
}